// Round 3
// baseline (520.745 us; speedup 1.0000x reference)
//
#include <hip/hip_runtime.h>
#include <cstdint>
#include <cstddef>

#define H2 1024
#define TT 512
#define NSTEPS 64
#define RBLK 32    // recurrence blocks
#define RTHR 512   // threads per block
#define PREBLK 224 // pre-pass worker blocks (wconv + transpose)
#define TOTBLK (RBLK + PREBLK)

using floatx4 = __attribute__((__ext_vector_type__(4))) float;
using half8   = __attribute__((__ext_vector_type__(8))) _Float16;
using half4   = __attribute__((__ext_vector_type__(4))) _Float16;
typedef unsigned long long u64;

__device__ __forceinline__ float tanh_fast(float x) {
  return 1.0f - 2.0f / (__expf(2.0f * x) + 1.0f);
}

#define GLDS16(gp, lp)                                                         \
  __builtin_amdgcn_global_load_lds(                                            \
      (const __attribute__((address_space(1))) void*)(gp),                     \
      (__attribute__((address_space(3))) void*)(lp), 16, 0, 0)

// ---------------------------------------------------------------------------
// Fused cooperative kernel:
//   blocks [0,32):   recurrence, data-as-flag + single poller wave per block.
//   blocks [32,256): wconv (W fp32->fp16) + transpose_h (h -> hhT fp16),
//                    overlapped under the latency-bound recurrence.
//
// Recurrence layout (cuts LDS dot traffic 4x vs R2):
//   wave w owns rows r0=32b+4w..+3; lane l owns cols {256j+4l+c, j<4,c<4}.
//   Poller (wave 0) polls prev step's 4KB via agent-scope u64 loads with
//   per-32bit poison checks, stages LINEAR into LDS (ds_write_b64, 2-way
//   free), computes ||z||^2 butterfly. After one barrier, every wave reads
//   just 64B/lane of z (4x ds_read_b128, stride-16B conflict-free), does
//   64 FMAs against its register-resident W slice, 6-level butterfly over
//   the full wave (lanes cover all 1024 cols exactly once), lane 0 publishes
//   4 rows as 2 agent-scope u64 stores. No trailing barrier (double buffer);
//   detect-on-own-rows bounds intra-block skew to < 1 step.
// ---------------------------------------------------------------------------
__global__ __launch_bounds__(RTHR, 1) void recur_pre_kernel(
    const float* __restrict__ W, const float* __restrict__ bias,
    const float* __restrict__ u0, float* __restrict__ vbuf,
    float* __restrict__ norm2, _Float16* __restrict__ Wh,
    const float* __restrict__ h, _Float16* __restrict__ hhT) {
  __shared__ __align__(16) char smem[2 * 16640];  // max(recur 8.2KB, 2 tiles)
  int tid = threadIdx.x;

  if (blockIdx.x < RBLK) {
    // ------------------------- recurrence role ---------------------------
    float* ub = (float*)smem;              // [2][1024] double-buffered z
    float* bredn = (float*)(smem + 8192);  // [2] norm^2
    int w = tid >> 6, l = tid & 63;
    int r0 = blockIdx.x * RBLK + w * 4;  // this wave's 4 rows

    // W slice in registers: wreg[p*4+j] = W[r0+p][256j+4l .. +3]
    floatx4 wreg[16];
    float blv[4];
#pragma unroll
    for (int p = 0; p < 4; ++p) {
      const float* wr = W + ((size_t)(r0 + p) << 10) + 4 * l;
#pragma unroll
      for (int j = 0; j < 4; ++j)
        wreg[p * 4 + j] = *(const floatx4*)(wr + 256 * j);
      blv[p] = bias[r0 + p];
    }
#pragma unroll
    for (int j = 0; j < 16; ++j) asm volatile("" : "+v"(wreg[j]));

    for (int i = 0; i < NSTEPS; ++i) {
      float* cb = ub + (i & 1) * 1024;
      float rs;
      if (i == 0) {
        if (w == 0) {
#pragma unroll
          for (int j = 0; j < 4; ++j) {
            floatx4 v = *((const floatx4*)u0 + l + 64 * j);
            *(floatx4*)(cb + 4 * l + 256 * j) = v;
          }
        }
        __syncthreads();
        rs = 1.0f;
      } else {
        if (w == 0) {
          const u64* src = (const u64*)(vbuf + ((size_t)(i - 1) << 10)) + l;
          u64 v[8];
          for (;;) {  // hot poll, no sleep: min detect latency
            bool ok = true;
#pragma unroll
            for (int j = 0; j < 8; ++j) {
              v[j] = __hip_atomic_load(src + 64 * j, __ATOMIC_RELAXED,
                                       __HIP_MEMORY_SCOPE_AGENT);
              ok &= ((unsigned)(v[j] & 0xFFFFFFFFu) != 0xFFFFFFFFu) &
                    ((unsigned)(v[j] >> 32) != 0xFFFFFFFFu);
            }
            if (__all(ok)) break;
          }
          float sq = 0.f;
#pragma unroll
          for (int j = 0; j < 8; ++j) {
            *(u64*)(cb + 2 * l + 128 * j) = v[j];  // linear stage
            float f0 =
                __builtin_bit_cast(float, (unsigned)(v[j] & 0xFFFFFFFFu));
            float f1 = __builtin_bit_cast(float, (unsigned)(v[j] >> 32));
            sq += f0 * f0 + f1 * f1;
          }
#pragma unroll
          for (int off = 1; off <= 32; off <<= 1)
            sq += __shfl_xor(sq, off, 64);
          if (l == 0) bredn[i & 1] = sq;
        }
        __syncthreads();
        float nrm = bredn[i & 1];
        rs = 1.0f / fmaxf(sqrtf(nrm), 1e-12f);
        if (blockIdx.x == 0 && tid == 64) norm2[i - 1] = nrm;  // off-path wave
      }

      // dot: 4 ds_read_b128 of z (scattered cols) x register W, 64 FMA
      float acc0 = 0.f, acc1 = 0.f, acc2 = 0.f, acc3 = 0.f;
#pragma unroll
      for (int j = 0; j < 4; ++j) {
        floatx4 zv = *(const floatx4*)(cb + 256 * j + 4 * l);
        floatx4 w0 = wreg[0 * 4 + j], w1 = wreg[1 * 4 + j];
        floatx4 w2 = wreg[2 * 4 + j], w3 = wreg[3 * 4 + j];
        acc0 += w0.x * zv.x + w0.y * zv.y + w0.z * zv.z + w0.w * zv.w;
        acc1 += w1.x * zv.x + w1.y * zv.y + w1.z * zv.z + w1.w * zv.w;
        acc2 += w2.x * zv.x + w2.y * zv.y + w2.z * zv.z + w2.w * zv.w;
        acc3 += w3.x * zv.x + w3.y * zv.y + w3.z * zv.z + w3.w * zv.w;
      }
#pragma unroll
      for (int off = 1; off <= 32; off <<= 1) {
        acc0 += __shfl_xor(acc0, off, 64);
        acc1 += __shfl_xor(acc1, off, 64);
        acc2 += __shfl_xor(acc2, off, 64);
        acc3 += __shfl_xor(acc3, off, 64);
      }
      if (l == 0) {
        float y0 = acc0 * rs + blv[0], y1 = acc1 * rs + blv[1];
        float y2 = acc2 * rs + blv[2], y3 = acc3 * rs + blv[3];
        u64 a01 = ((u64)__builtin_bit_cast(unsigned, y1) << 32) |
                  (u64)__builtin_bit_cast(unsigned, y0);
        u64 a23 = ((u64)__builtin_bit_cast(unsigned, y3) << 32) |
                  (u64)__builtin_bit_cast(unsigned, y2);
        u64* dst = (u64*)(vbuf + ((size_t)i << 10) + r0);
        __hip_atomic_store(dst, a01, __ATOMIC_RELAXED,
                           __HIP_MEMORY_SCOPE_AGENT);
        __hip_atomic_store(dst + 1, a23, __ATOMIC_RELAXED,
                           __HIP_MEMORY_SCOPE_AGENT);
      }
      // no trailing barrier: double-buffered LDS; poller can't pass step i+1
      // detect until this block's own rows are published.
    }

    // tail: ||y_63||^2 for gemm2's epilogue
    if (blockIdx.x == 0 && w == 0) {
      const u64* src = (const u64*)(vbuf + ((size_t)(NSTEPS - 1) << 10)) + l;
      u64 v[8];
      for (;;) {
        bool ok = true;
#pragma unroll
        for (int j = 0; j < 8; ++j) {
          v[j] = __hip_atomic_load(src + 64 * j, __ATOMIC_RELAXED,
                                   __HIP_MEMORY_SCOPE_AGENT);
          ok &= ((unsigned)(v[j] & 0xFFFFFFFFu) != 0xFFFFFFFFu) &
                ((unsigned)(v[j] >> 32) != 0xFFFFFFFFu);
        }
        if (__all(ok)) break;
      }
      float sq = 0.f;
#pragma unroll
      for (int j = 0; j < 8; ++j) {
        float f0 = __builtin_bit_cast(float, (unsigned)(v[j] & 0xFFFFFFFFu));
        float f1 = __builtin_bit_cast(float, (unsigned)(v[j] >> 32));
        sq += f0 * f0 + f1 * f1;
      }
#pragma unroll
      for (int off = 1; off <= 32; off <<= 1) sq += __shfl_xor(sq, off, 64);
      if (l == 0) norm2[NSTEPS - 1] = sq;
    }
  } else {
    // ------------------- pre-pass role (overlapped) ----------------------
    int pb = blockIdx.x - RBLK;  // 0..223

    // wconv: W fp32 -> fp16 (1M elems as 256K float4 quads)
    const floatx4* Wv = (const floatx4*)W;
    for (int idx = pb * RTHR + tid; idx < H2 * H2 / 4; idx += PREBLK * RTHR) {
      floatx4 v = Wv[idx];
      half4 o = {(_Float16)v.x, (_Float16)v.y, (_Float16)v.z, (_Float16)v.w};
      ((half4*)Wh)[idx] = o;
    }

    // transpose_h: 8192 64x64 tiles, 2 tiles per block-iteration
    int sub = tid >> 8, ltid = tid & 255;
    float(*tile)[65] = (float(*)[65])(smem + sub * 16640);
    int dr = ltid >> 4, tc = (ltid & 15) << 2;
    int tr = ltid >> 3, seg = ltid & 7;
    for (int base = pb * 2; base < 8192; base += PREBLK * 2) {
      int tidx = base + sub;
      bool act = tidx < 8192;
      int n = tidx >> 7, rem = tidx & 127;
      int d0 = (rem & 15) << 6, t0 = ((rem >> 4) & 7) << 6;
      if (act) {
        const float* hb = h + ((size_t)n * H2 + d0) * TT + t0;
#pragma unroll
        for (int p = 0; p < 4; ++p) {
          floatx4 v = *(const floatx4*)(hb + (size_t)(dr + p * 16) * TT + tc);
          tile[dr + p * 16][tc] = v.x;
          tile[dr + p * 16][tc + 1] = v.y;
          tile[dr + p * 16][tc + 2] = v.z;
          tile[dr + p * 16][tc + 3] = v.w;
        }
      }
      __syncthreads();
      if (act) {
        _Float16* ob = hhT + ((size_t)n * TT + t0) * H2 + d0;
#pragma unroll
        for (int p = 0; p < 2; ++p) {
          int t = tr + p * 32;
          half8 hv;
#pragma unroll
          for (int u = 0; u < 8; ++u) hv[u] = (_Float16)tile[seg * 8 + u][t];
          *(half8*)(ob + (size_t)t * H2 + seg * 8) = hv;
        }
      }
      __syncthreads();
    }
  }
}

// ---------------------------------------------------------------------------
// GEMM from pre-converted fp16 operands, global_load_lds staging.
// C[e,t] = sum_d Wh[e,d]*hhT[n,t,d]; epilogue tanh + u_ws dot -> scores atomics
// ---------------------------------------------------------------------------
__global__ __launch_bounds__(256) void gemm2(
    const _Float16* __restrict__ Wh, const _Float16* __restrict__ hhT,
    const float* __restrict__ bias, const float* __restrict__ vbuf,
    const float* __restrict__ norm2, float* __restrict__ scores) {
  int x = blockIdx.x;
  int xcd = x & 7, slot = x >> 3;
  int e_t = slot & 7;
  int tn = xcd * 32 + (slot >> 3);
  int t_t = tn & 3, n = tn >> 2;
  int e_base = e_t * 128, t_base = t_t * 128;

  int tid = threadIdx.x, lane = tid & 63, w = tid >> 6;
  int q = lane >> 4, m = lane & 15;
  int eoff = (w & 1) * 64, toff = (w >> 1) * 64;

  __shared__ __align__(16) _Float16 Ash[128 * 32];
  __shared__ __align__(16) _Float16 Bsh[128 * 32];

  floatx4 zero = {0.f, 0.f, 0.f, 0.f};
  floatx4 acc[4][4];
#pragma unroll
  for (int i = 0; i < 4; ++i)
#pragma unroll
    for (int j = 0; j < 4; ++j) acc[i][j] = zero;

  int rl = lane >> 2, kseg = lane & 3;
  const _Float16* gA0 =
      Wh + (((size_t)(e_base + w * 32 + rl)) << 10) + kseg * 8;
  const _Float16* gA1 = gA0 + ((size_t)16 << 10);
  const _Float16* gB0 = hhT + ((size_t)n << 19) +
                        (((size_t)(t_base + w * 32 + rl)) << 10) + kseg * 8;
  const _Float16* gB1 = gB0 + ((size_t)16 << 10);
  _Float16* lA0 = Ash + (w * 32) * 32;
  _Float16* lA1 = lA0 + 16 * 32;
  _Float16* lB0 = Bsh + (w * 32) * 32;
  _Float16* lB1 = lB0 + 16 * 32;

  for (int k0 = 0; k0 < H2; k0 += 32) {
    GLDS16(gA0 + k0, lA0);
    GLDS16(gA1 + k0, lA1);
    GLDS16(gB0 + k0, lB0);
    GLDS16(gB1 + k0, lB1);
    __syncthreads();

    half8 af[4], bf[4];
#pragma unroll
    for (int i = 0; i < 4; ++i)
      af[i] = *(const half8*)&Ash[(eoff + i * 16 + m) * 32 + q * 8];
#pragma unroll
    for (int j = 0; j < 4; ++j)
      bf[j] = *(const half8*)&Bsh[(toff + j * 16 + m) * 32 + q * 8];
#pragma unroll
    for (int i = 0; i < 4; ++i)
#pragma unroll
      for (int j = 0; j < 4; ++j)
        acc[i][j] =
            __builtin_amdgcn_mfma_f32_16x16x32_f16(af[i], bf[j], acc[i][j], 0, 0, 0);
    __syncthreads();
  }

  float* uloc = (float*)Ash;
  float* bloc = uloc + 128;
  if (tid < 128) {
    float rsn = 1.0f / fmaxf(sqrtf(norm2[n]), 1e-12f);
    uloc[tid] = vbuf[((size_t)n << 10) + e_base + tid] * rsn;
    bloc[tid] = bias[e_base + tid];
  }
  __syncthreads();

  float part[4] = {0.f, 0.f, 0.f, 0.f};
#pragma unroll
  for (int i = 0; i < 4; ++i) {
#pragma unroll
    for (int reg = 0; reg < 4; ++reg) {
      int el = eoff + i * 16 + q * 4 + reg;
      float ubv = uloc[el];
      float bbv = bloc[el];
#pragma unroll
      for (int j = 0; j < 4; ++j) {
        float y = acc[i][j][reg] + bbv;
        part[j] += tanh_fast(y) * ubv;
      }
    }
  }
#pragma unroll
  for (int j = 0; j < 4; ++j) {
    part[j] += __shfl_xor(part[j], 16, 64);
    part[j] += __shfl_xor(part[j], 32, 64);
    if (lane < 16) {
      int t = t_base + toff + j * 16 + lane;
      atomicAdd(&scores[(size_t)n * TT + t], part[j]);
    }
  }
}

// ---------------------------------------------------------------------------
// Fused softmax + weighted sum
// ---------------------------------------------------------------------------
__global__ __launch_bounds__(256) void out_kernel(
    const float* __restrict__ h, const float* __restrict__ scores,
    float* __restrict__ out) {
  int n = blockIdx.y;
  int ds = blockIdx.x;
  int tid = threadIdx.x;
  int w = tid >> 6, lane = tid & 63;

  __shared__ float sa[TT];
  __shared__ float wred[8];

  float s0 = scores[(size_t)n * TT + tid];
  float s1 = scores[(size_t)n * TT + 256 + tid];

  float mx = fmaxf(s0, s1);
#pragma unroll
  for (int off = 32; off >= 1; off >>= 1) mx = fmaxf(mx, __shfl_xor(mx, off, 64));
  if (lane == 0) wred[w] = mx;
  __syncthreads();
  mx = fmaxf(fmaxf(wred[0], wred[1]), fmaxf(wred[2], wred[3]));

  float e0 = __expf(s0 - mx);
  float e1 = __expf(s1 - mx);
  float ssum = e0 + e1;
#pragma unroll
  for (int off = 32; off >= 1; off >>= 1) ssum += __shfl_xor(ssum, off, 64);
  if (lane == 0) wred[4 + w] = ssum;
  __syncthreads();
  ssum = wred[4] + wred[5] + wred[6] + wred[7];
  float inv = 1.0f / ssum;
  sa[tid] = e0 * inv;
  sa[tid + 256] = e1 * inv;
  __syncthreads();

  int d0 = ds * 64 + w * 16;
  const float4* hb = reinterpret_cast<const float4*>(h + (size_t)n * H2 * TT);
#pragma unroll 1
  for (int rr = 0; rr < 16; ++rr) {
    int d = d0 + rr;
    const float4* hr = hb + (size_t)d * (TT / 4);
    float4 a4 = hr[lane];
    float4 b4 = hr[64 + lane];
    int t0 = 4 * lane;
    float acc = a4.x * sa[t0] + a4.y * sa[t0 + 1] + a4.z * sa[t0 + 2] +
                a4.w * sa[t0 + 3] + b4.x * sa[256 + t0] +
                b4.y * sa[256 + t0 + 1] + b4.z * sa[256 + t0 + 2] +
                b4.w * sa[256 + t0 + 3];
#pragma unroll
    for (int off = 1; off <= 32; off <<= 1) acc += __shfl_xor(acc, off, 64);
    if (lane == 0) out[(size_t)n * H2 + d] = acc;
  }
}

// ---------------------------------------------------------------------------
extern "C" void kernel_launch(void* const* d_in, const int* in_sizes, int n_in,
                              void* d_out, int out_size, void* d_ws, size_t ws_size,
                              hipStream_t stream) {
  const float* h    = (const float*)d_in[0];  // (64, 1024, 512)
  const float* W    = (const float*)d_in[1];  // (1024, 1024)
  const float* bias = (const float*)d_in[2];  // (1024,)
  const float* u0   = (const float*)d_in[3];  // (1024,)
  float* out = (float*)d_out;                 // (64, 1024)

  float* wsf    = (float*)d_ws;
  float* norm2  = wsf;                          // 64
  float* scores = wsf + 64;                     // 64*512
  float* vbuf   = wsf + 64 + NSTEPS * TT;       // 64*1024
  unsigned* ctr = (unsigned*)(vbuf + (size_t)NSTEPS * H2);  // legacy pad slot
  float* after_ctr = (float*)(ctr + 16);        // pad
  _Float16* Wh  = (_Float16*)after_ctr;                       // 1M halfs
  _Float16* hhT = Wh + (size_t)H2 * H2;                       // 32M halfs

  // zero norm2 + scores (atomically accumulated); poison vbuf for data-polling
  hipMemsetAsync(d_ws, 0, (size_t)(64 + NSTEPS * TT) * sizeof(float), stream);
  hipMemsetAsync(vbuf, 0xFF, (size_t)NSTEPS * H2 * sizeof(float), stream);

  // fused cooperative launch: recurrence (blocks 0-31) + pre-passes (32-255)
  {
    const float* Wp = W; const float* bp = bias; const float* up = u0;
    float* vp = vbuf; float* np = norm2;
    _Float16* whp = Wh; const float* hp = h; _Float16* htp = hhT;
    void* kargs[] = {&Wp, &bp, &up, &vp, &np, &whp, &hp, &htp};
    hipLaunchCooperativeKernel((void*)recur_pre_kernel, dim3(TOTBLK),
                               dim3(RTHR), kargs, 0, stream);
  }

  gemm2<<<dim3(2048), dim3(256), 0, stream>>>(Wh, hhT, bias, vbuf, norm2,
                                              scores);
  out_kernel<<<dim3(16, 64), dim3(256), 0, stream>>>(h, scores, out);

  (void)in_sizes; (void)n_in; (void)out_size; (void)ws_size;
}

// Round 4
// 489.120 us; speedup vs baseline: 1.0647x; 1.0647x over previous
//
#include <hip/hip_runtime.h>
#include <cstdint>
#include <cstddef>

#define H2 1024
#define TT 512
#define NSTEPS 64
#define RBLK 32    // recurrence blocks
#define RTHR 512   // threads per block
#define PREBLK 224 // pre-pass worker blocks
#define TOTBLK 256
#define NTILES 2048u  // 64 n * 8 e-tiles * 4 t-tiles

using floatx4 = __attribute__((__ext_vector_type__(4))) float;
using half8   = __attribute__((__ext_vector_type__(8))) _Float16;
using half4   = __attribute__((__ext_vector_type__(4))) _Float16;
typedef unsigned long long u64;

__device__ __forceinline__ float tanh_fast(float x) {
  return 1.0f - 2.0f / (__expf(2.0f * x) + 1.0f);
}

#define GLDS16(gp, lp)                                                         \
  __builtin_amdgcn_global_load_lds(                                            \
      (const __attribute__((address_space(1))) void*)(gp),                     \
      (__attribute__((address_space(3))) void*)(lp), 16, 0, 0)

// ---------------------------------------------------------------------------
// ONE cooperative kernel for recurrence + pre-passes + GEMM (work-queue):
//   blocks [0,32):   64-step recurrence (data-as-flag, single poller wave),
//                    then join the GEMM tile queue.
//   blocks [32,256): wconv + transpose_h with AGENT-SCOPE stores (required:
//                    per-XCD L2s are not coherent; normal stores would sit
//                    dirty in the writer's L2 and GEMM readers on other XCDs
//                    would fetch stale IC data), then release-increment
//                    `done`, then join the GEMM tile queue.
// GEMM: 512-thread block = two independent 256-thread halves, each the
// proven gemm2 structure (identical K trip count -> full-block barriers are
// convergent). Tiles popped in pairs (same n, same t-panel -> L2-hot B for
// the second half). Epilogue polls norm2[n]/vbuf[n] data-as-flag (poisoned).
// This removes the recurrence AND the pre-passes from the serialized
// critical path: total ~= max(recur, transpose+gemm) + out.
// ---------------------------------------------------------------------------
__global__ __launch_bounds__(RTHR, 1) void fused_kernel(
    const float* __restrict__ W, const float* __restrict__ bias,
    const float* __restrict__ u0, float* __restrict__ vbuf,
    float* __restrict__ norm2, _Float16* __restrict__ Wh,
    const float* __restrict__ h, _Float16* __restrict__ hhT,
    float* __restrict__ scores, unsigned* __restrict__ ctrs) {
  __shared__ __align__(16) char smem[33792];
  int tid = threadIdx.x;
  unsigned* done  = ctrs;       // transpose/wconv completion count
  unsigned* queue = ctrs + 16;  // gemm tile queue (separate 64B line)

  if (blockIdx.x < RBLK) {
    // ------------------------- recurrence role ---------------------------
    float* ub = (float*)smem;              // [2][1024] double-buffered z
    float* bredn = (float*)(smem + 8192);  // [2] norm^2
    int w = tid >> 6, l = tid & 63;
    int r0 = blockIdx.x * RBLK + w * 4;  // this wave's 4 rows

    floatx4 wreg[16];
    float blv[4];
#pragma unroll
    for (int p = 0; p < 4; ++p) {
      const float* wr = W + ((size_t)(r0 + p) << 10) + 4 * l;
#pragma unroll
      for (int j = 0; j < 4; ++j)
        wreg[p * 4 + j] = *(const floatx4*)(wr + 256 * j);
      blv[p] = bias[r0 + p];
    }
#pragma unroll
    for (int j = 0; j < 16; ++j) asm volatile("" : "+v"(wreg[j]));

    for (int i = 0; i < NSTEPS; ++i) {
      float* cb = ub + (i & 1) * 1024;
      float rs;
      if (i == 0) {
        if (w == 0) {
#pragma unroll
          for (int j = 0; j < 4; ++j) {
            floatx4 v = *((const floatx4*)u0 + l + 64 * j);
            *(floatx4*)(cb + 4 * l + 256 * j) = v;
          }
        }
        __syncthreads();
        rs = 1.0f;
      } else {
        if (w == 0) {
          const u64* src = (const u64*)(vbuf + ((size_t)(i - 1) << 10)) + l;
          u64 v[8];
          for (;;) {
            bool ok = true;
#pragma unroll
            for (int j = 0; j < 8; ++j) {
              v[j] = __hip_atomic_load(src + 64 * j, __ATOMIC_RELAXED,
                                       __HIP_MEMORY_SCOPE_AGENT);
              ok &= ((unsigned)(v[j] & 0xFFFFFFFFu) != 0xFFFFFFFFu) &
                    ((unsigned)(v[j] >> 32) != 0xFFFFFFFFu);
            }
            if (__all(ok)) break;
            __builtin_amdgcn_s_sleep(1);
          }
          float sq = 0.f;
#pragma unroll
          for (int j = 0; j < 8; ++j) {
            *(u64*)(cb + 2 * l + 128 * j) = v[j];
            float f0 =
                __builtin_bit_cast(float, (unsigned)(v[j] & 0xFFFFFFFFu));
            float f1 = __builtin_bit_cast(float, (unsigned)(v[j] >> 32));
            sq += f0 * f0 + f1 * f1;
          }
#pragma unroll
          for (int off = 1; off <= 32; off <<= 1)
            sq += __shfl_xor(sq, off, 64);
          if (l == 0) bredn[i & 1] = sq;
        }
        __syncthreads();
        float nrm = bredn[i & 1];
        rs = 1.0f / fmaxf(sqrtf(nrm), 1e-12f);
        if (blockIdx.x == 0 && tid == 64) {
          unsigned nb = __builtin_bit_cast(unsigned, nrm);
          __hip_atomic_store((unsigned*)(norm2 + (i - 1)), nb,
                             __ATOMIC_RELAXED, __HIP_MEMORY_SCOPE_AGENT);
        }
      }

      float acc0 = 0.f, acc1 = 0.f, acc2 = 0.f, acc3 = 0.f;
#pragma unroll
      for (int j = 0; j < 4; ++j) {
        floatx4 zv = *(const floatx4*)(cb + 256 * j + 4 * l);
        floatx4 w0 = wreg[0 * 4 + j], w1 = wreg[1 * 4 + j];
        floatx4 w2 = wreg[2 * 4 + j], w3 = wreg[3 * 4 + j];
        acc0 += w0.x * zv.x + w0.y * zv.y + w0.z * zv.z + w0.w * zv.w;
        acc1 += w1.x * zv.x + w1.y * zv.y + w1.z * zv.z + w1.w * zv.w;
        acc2 += w2.x * zv.x + w2.y * zv.y + w2.z * zv.z + w2.w * zv.w;
        acc3 += w3.x * zv.x + w3.y * zv.y + w3.z * zv.z + w3.w * zv.w;
      }
#pragma unroll
      for (int off = 1; off <= 32; off <<= 1) {
        acc0 += __shfl_xor(acc0, off, 64);
        acc1 += __shfl_xor(acc1, off, 64);
        acc2 += __shfl_xor(acc2, off, 64);
        acc3 += __shfl_xor(acc3, off, 64);
      }
      if (l == 0) {
        float y0 = acc0 * rs + blv[0], y1 = acc1 * rs + blv[1];
        float y2 = acc2 * rs + blv[2], y3 = acc3 * rs + blv[3];
        u64 a01 = ((u64)__builtin_bit_cast(unsigned, y1) << 32) |
                  (u64)__builtin_bit_cast(unsigned, y0);
        u64 a23 = ((u64)__builtin_bit_cast(unsigned, y3) << 32) |
                  (u64)__builtin_bit_cast(unsigned, y2);
        u64* dst = (u64*)(vbuf + ((size_t)i << 10) + r0);
        __hip_atomic_store(dst, a01, __ATOMIC_RELAXED,
                           __HIP_MEMORY_SCOPE_AGENT);
        __hip_atomic_store(dst + 1, a23, __ATOMIC_RELAXED,
                           __HIP_MEMORY_SCOPE_AGENT);
      }
    }

    // tail: ||y_63||^2
    if (blockIdx.x == 0 && (tid >> 6) == 0) {
      int l2 = tid & 63;
      const u64* src = (const u64*)(vbuf + ((size_t)(NSTEPS - 1) << 10)) + l2;
      u64 v[8];
      for (;;) {
        bool ok = true;
#pragma unroll
        for (int j = 0; j < 8; ++j) {
          v[j] = __hip_atomic_load(src + 64 * j, __ATOMIC_RELAXED,
                                   __HIP_MEMORY_SCOPE_AGENT);
          ok &= ((unsigned)(v[j] & 0xFFFFFFFFu) != 0xFFFFFFFFu) &
                ((unsigned)(v[j] >> 32) != 0xFFFFFFFFu);
        }
        if (__all(ok)) break;
        __builtin_amdgcn_s_sleep(1);
      }
      float sq = 0.f;
#pragma unroll
      for (int j = 0; j < 8; ++j) {
        float f0 = __builtin_bit_cast(float, (unsigned)(v[j] & 0xFFFFFFFFu));
        float f1 = __builtin_bit_cast(float, (unsigned)(v[j] >> 32));
        sq += f0 * f0 + f1 * f1;
      }
#pragma unroll
      for (int off = 1; off <= 32; off <<= 1) sq += __shfl_xor(sq, off, 64);
      if (l2 == 0) {
        unsigned nb = __builtin_bit_cast(unsigned, sq);
        __hip_atomic_store((unsigned*)(norm2 + (NSTEPS - 1)), nb,
                           __ATOMIC_RELAXED, __HIP_MEMORY_SCOPE_AGENT);
      }
    }
    __syncthreads();
  } else {
    // ------------------- pre-pass role (overlapped) ----------------------
    int pb = blockIdx.x - RBLK;  // 0..223

    // wconv: W fp32 -> fp16, AGENT stores (cross-XCD within-kernel visibility)
    const floatx4* Wv = (const floatx4*)W;
    for (int idx = pb * RTHR + tid; idx < H2 * H2 / 4; idx += PREBLK * RTHR) {
      floatx4 v = Wv[idx];
      half4 o = {(_Float16)v.x, (_Float16)v.y, (_Float16)v.z, (_Float16)v.w};
      __hip_atomic_store((u64*)Wh + idx, __builtin_bit_cast(u64, o),
                         __ATOMIC_RELAXED, __HIP_MEMORY_SCOPE_AGENT);
    }

    // transpose_h: 8192 64x64 tiles, 2 per block-iteration, AGENT stores
    int sub = tid >> 8, ltid = tid & 255;
    float(*tile)[65] = (float(*)[65])(smem + sub * 16640);
    int dr = ltid >> 4, tc = (ltid & 15) << 2;
    int tr = ltid >> 3, seg = ltid & 7;
    for (int base = pb * 2; base < 8192; base += PREBLK * 2) {
      int tidx = base + sub;
      bool act = tidx < 8192;
      int n = tidx >> 7, rem = tidx & 127;
      int d0 = (rem & 15) << 6, t0 = ((rem >> 4) & 7) << 6;
      if (act) {
        const float* hb = h + ((size_t)n * H2 + d0) * TT + t0;
#pragma unroll
        for (int p = 0; p < 4; ++p) {
          floatx4 v = *(const floatx4*)(hb + (size_t)(dr + p * 16) * TT + tc);
          tile[dr + p * 16][tc] = v.x;
          tile[dr + p * 16][tc + 1] = v.y;
          tile[dr + p * 16][tc + 2] = v.z;
          tile[dr + p * 16][tc + 3] = v.w;
        }
      }
      __syncthreads();
      if (act) {
        _Float16* ob = hhT + ((size_t)n * TT + t0) * H2 + d0;
#pragma unroll
        for (int p = 0; p < 2; ++p) {
          int t = tr + p * 32;
          union { half8 v; u64 u[2]; } hu;
#pragma unroll
          for (int u = 0; u < 8; ++u) hu.v[u] = (_Float16)tile[seg * 8 + u][t];
          u64* op = (u64*)(ob + (size_t)t * H2 + seg * 8);
          __hip_atomic_store(op, hu.u[0], __ATOMIC_RELAXED,
                             __HIP_MEMORY_SCOPE_AGENT);
          __hip_atomic_store(op + 1, hu.u[1], __ATOMIC_RELAXED,
                             __HIP_MEMORY_SCOPE_AGENT);
        }
      }
      __syncthreads();
    }
    asm volatile("s_waitcnt vmcnt(0)" ::: "memory");
    __syncthreads();
    if (tid == 0)
      __hip_atomic_fetch_add(done, 1u, __ATOMIC_RELEASE,
                             __HIP_MEMORY_SCOPE_AGENT);
  }

  // ---------------- GEMM phase: all blocks, tile work-queue ----------------
  if (tid == 0) {
    while (__hip_atomic_load(done, __ATOMIC_ACQUIRE,
                             __HIP_MEMORY_SCOPE_AGENT) < (unsigned)PREBLK)
      __builtin_amdgcn_s_sleep(2);
  }
  __syncthreads();

  int half = tid >> 8, tid2 = tid & 255;
  _Float16* Ash = (_Float16*)(smem + half * 16384);
  _Float16* Bsh = Ash + 4096;
  unsigned* tslot = (unsigned*)(smem + 32768);

  int lane = tid2 & 63, w2 = tid2 >> 6;
  int q = lane >> 4, m = lane & 15;
  int eoff = (w2 & 1) * 64, toff = (w2 >> 1) * 64;
  int rl = lane >> 2, kseg = lane & 3;
  _Float16* lA0 = Ash + (w2 * 32) * 32;
  _Float16* lA1 = lA0 + 16 * 32;
  _Float16* lB0 = Bsh + (w2 * 32) * 32;
  _Float16* lB1 = lB0 + 16 * 32;

  for (;;) {
    if (tid == 0) {
      unsigned q0 = atomicAdd(queue, 2u);
      tslot[0] = q0;
      tslot[1] = q0 + 1u;
    }
    __syncthreads();
    if (tslot[0] >= NTILES) break;  // pops are even: both halves valid or none
    unsigned tau = tslot[half];
    int n = (int)(tau >> 5);
    int rem = (int)(tau & 31u);
    int e_base = (rem & 7) << 7, t_base = (rem >> 3) << 7;

    const _Float16* gA0 =
        Wh + (((size_t)(e_base + w2 * 32 + rl)) << 10) + kseg * 8;
    const _Float16* gA1 = gA0 + ((size_t)16 << 10);
    const _Float16* gB0 = hhT + ((size_t)n << 19) +
                          (((size_t)(t_base + w2 * 32 + rl)) << 10) + kseg * 8;
    const _Float16* gB1 = gB0 + ((size_t)16 << 10);

    floatx4 zero = {0.f, 0.f, 0.f, 0.f};
    floatx4 acc[4][4];
#pragma unroll
    for (int i = 0; i < 4; ++i)
#pragma unroll
      for (int j = 0; j < 4; ++j) acc[i][j] = zero;

    for (int k0 = 0; k0 < H2; k0 += 32) {
      GLDS16(gA0 + k0, lA0);
      GLDS16(gA1 + k0, lA1);
      GLDS16(gB0 + k0, lB0);
      GLDS16(gB1 + k0, lB1);
      __syncthreads();

      half8 af[4], bf[4];
#pragma unroll
      for (int i = 0; i < 4; ++i)
        af[i] = *(const half8*)&Ash[(eoff + i * 16 + m) * 32 + q * 8];
#pragma unroll
      for (int j = 0; j < 4; ++j)
        bf[j] = *(const half8*)&Bsh[(toff + j * 16 + m) * 32 + q * 8];
#pragma unroll
      for (int i = 0; i < 4; ++i)
#pragma unroll
        for (int j = 0; j < 4; ++j)
          acc[i][j] = __builtin_amdgcn_mfma_f32_16x16x32_f16(af[i], bf[j],
                                                             acc[i][j], 0, 0, 0);
      __syncthreads();
    }

    // epilogue: poll norm2[n]/vbuf (data-as-flag; ~always ready by now)
    float* uloc = (float*)Ash;
    float* bloc = uloc + 128;
    if (tid2 < 128) {
      float nn;
      for (;;) {
        unsigned b = __hip_atomic_load((const unsigned*)(norm2 + n),
                                       __ATOMIC_RELAXED,
                                       __HIP_MEMORY_SCOPE_AGENT);
        if (b != 0xFFFFFFFFu) {
          nn = __builtin_bit_cast(float, b);
          break;
        }
        __builtin_amdgcn_s_sleep(1);
      }
      float rsn = 1.0f / fmaxf(sqrtf(nn), 1e-12f);
      const unsigned* vp =
          (const unsigned*)(vbuf + ((size_t)n << 10) + e_base) + tid2;
      float vv;
      for (;;) {
        unsigned b =
            __hip_atomic_load(vp, __ATOMIC_RELAXED, __HIP_MEMORY_SCOPE_AGENT);
        if (b != 0xFFFFFFFFu) {
          vv = __builtin_bit_cast(float, b);
          break;
        }
        __builtin_amdgcn_s_sleep(1);
      }
      uloc[tid2] = vv * rsn;
      bloc[tid2] = bias[e_base + tid2];
    }
    __syncthreads();

    float part[4] = {0.f, 0.f, 0.f, 0.f};
#pragma unroll
    for (int i = 0; i < 4; ++i) {
#pragma unroll
      for (int reg = 0; reg < 4; ++reg) {
        int el = eoff + i * 16 + q * 4 + reg;
        float ubv = uloc[el];
        float bbv = bloc[el];
#pragma unroll
        for (int j = 0; j < 4; ++j) {
          float y = acc[i][j][reg] + bbv;
          part[j] += tanh_fast(y) * ubv;
        }
      }
    }
#pragma unroll
    for (int j = 0; j < 4; ++j) {
      part[j] += __shfl_xor(part[j], 16, 64);
      part[j] += __shfl_xor(part[j], 32, 64);
      if (lane < 16) {
        int t = t_base + toff + j * 16 + lane;
        atomicAdd(&scores[(size_t)n * TT + t], part[j]);
      }
    }
    __syncthreads();  // epilogue LDS reads done before next pop/staging
  }
}

// ---------------------------------------------------------------------------
// Fused softmax + weighted sum
// ---------------------------------------------------------------------------
__global__ __launch_bounds__(256) void out_kernel(
    const float* __restrict__ h, const float* __restrict__ scores,
    float* __restrict__ out) {
  int n = blockIdx.y;
  int ds = blockIdx.x;
  int tid = threadIdx.x;
  int w = tid >> 6, lane = tid & 63;

  __shared__ float sa[TT];
  __shared__ float wred[8];

  float s0 = scores[(size_t)n * TT + tid];
  float s1 = scores[(size_t)n * TT + 256 + tid];

  float mx = fmaxf(s0, s1);
#pragma unroll
  for (int off = 32; off >= 1; off >>= 1) mx = fmaxf(mx, __shfl_xor(mx, off, 64));
  if (lane == 0) wred[w] = mx;
  __syncthreads();
  mx = fmaxf(fmaxf(wred[0], wred[1]), fmaxf(wred[2], wred[3]));

  float e0 = __expf(s0 - mx);
  float e1 = __expf(s1 - mx);
  float ssum = e0 + e1;
#pragma unroll
  for (int off = 32; off >= 1; off >>= 1) ssum += __shfl_xor(ssum, off, 64);
  if (lane == 0) wred[4 + w] = ssum;
  __syncthreads();
  ssum = wred[4] + wred[5] + wred[6] + wred[7];
  float inv = 1.0f / ssum;
  sa[tid] = e0 * inv;
  sa[tid + 256] = e1 * inv;
  __syncthreads();

  int d0 = ds * 64 + w * 16;
  const float4* hb = reinterpret_cast<const float4*>(h + (size_t)n * H2 * TT);
#pragma unroll 1
  for (int rr = 0; rr < 16; ++rr) {
    int d = d0 + rr;
    const float4* hr = hb + (size_t)d * (TT / 4);
    float4 a4 = hr[lane];
    float4 b4 = hr[64 + lane];
    int t0 = 4 * lane;
    float acc = a4.x * sa[t0] + a4.y * sa[t0 + 1] + a4.z * sa[t0 + 2] +
                a4.w * sa[t0 + 3] + b4.x * sa[256 + t0] +
                b4.y * sa[256 + t0 + 1] + b4.z * sa[256 + t0 + 2] +
                b4.w * sa[256 + t0 + 3];
#pragma unroll
    for (int off = 1; off <= 32; off <<= 1) acc += __shfl_xor(acc, off, 64);
    if (lane == 0) out[(size_t)n * H2 + d] = acc;
  }
}

// ---------------------------------------------------------------------------
extern "C" void kernel_launch(void* const* d_in, const int* in_sizes, int n_in,
                              void* d_out, int out_size, void* d_ws, size_t ws_size,
                              hipStream_t stream) {
  const float* h    = (const float*)d_in[0];  // (64, 1024, 512)
  const float* W    = (const float*)d_in[1];  // (1024, 1024)
  const float* bias = (const float*)d_in[2];  // (1024,)
  const float* u0   = (const float*)d_in[3];  // (1024,)
  float* out = (float*)d_out;                 // (64, 1024)

  float* wsf    = (float*)d_ws;
  float* norm2  = wsf;                          // 64 (poisoned)
  float* scores = wsf + 64;                     // 64*512 (zeroed)
  float* vbuf   = wsf + 64 + NSTEPS * TT;       // 64*1024 (poisoned)
  unsigned* ctrs = (unsigned*)(vbuf + (size_t)NSTEPS * H2);  // 32 uints
  float* after = (float*)(ctrs + 32);
  _Float16* Wh  = (_Float16*)after;             // 1M halfs
  _Float16* hhT = Wh + (size_t)H2 * H2;         // 32M halfs

  hipMemsetAsync(norm2, 0xFF, 64 * sizeof(float), stream);
  hipMemsetAsync(scores, 0, (size_t)NSTEPS * TT * sizeof(float), stream);
  hipMemsetAsync(vbuf, 0xFF, (size_t)NSTEPS * H2 * sizeof(float), stream);
  hipMemsetAsync(ctrs, 0, 32 * sizeof(unsigned), stream);

  {
    const float* Wp = W; const float* bp = bias; const float* up = u0;
    float* vp = vbuf; float* np = norm2;
    _Float16* whp = Wh; const float* hp = h; _Float16* htp = hhT;
    float* sp = scores; unsigned* cp = ctrs;
    void* kargs[] = {&Wp, &bp, &up, &vp, &np, &whp, &hp, &htp, &sp, &cp};
    hipLaunchCooperativeKernel((void*)fused_kernel, dim3(TOTBLK), dim3(RTHR),
                               kargs, 0, stream);
  }

  out_kernel<<<dim3(16, 64), dim3(256), 0, stream>>>(h, scores, out);

  (void)in_sizes; (void)n_in; (void)out_size; (void)ws_size;
}